// Round 12
// baseline (142.396 us; speedup 1.0000x reference)
//
#include <hip/hip_runtime.h>
#include <math.h>

typedef float f4 __attribute__((ext_vector_type(4)));

namespace {
constexpr int NZ = 48, NY = 256, NX = 512;
constexpr int SY = NX;            // y stride (elements)
constexpr int SZ = NX * NY;       // z stride (elements)
constexpr int NTOT = NZ * NY * NX;
constexpr float INV_DX = 1.0f / 100000.0f;
constexpr float INV_DY = 1.0f / 100000.0f;
constexpr float INV_DZ = 1.0f / 500.0f;
}

__device__ __forceinline__ f4 sp(float s) { return (f4){s, s, s, s}; }

__device__ __forceinline__ f4 ldv(const float* __restrict__ f, int e) {
    return *reinterpret_cast<const f4*>(f + e);
}

__device__ __forceinline__ f4 ntldv(const float* __restrict__ f, int e) {
    return __builtin_nontemporal_load(reinterpret_cast<const f4*>(f + e));
}

// ---- x-axis: window [L | C | R]; position x0 = first element of C ----
__device__ __forceinline__ void grad2x(f4 L, f4 C, f4 R, int x0, float inv_h,
                                       f4& g, f4& gg) {
    const float h1 = inv_h, h2 = 0.5f * inv_h;
    float win[12] = {L[0], L[1], L[2], L[3], C[0], C[1], C[2], C[3],
                     R[0], R[1], R[2], R[3]};
#pragma unroll
    for (int j = 0; j < 4; ++j) {
        g[j]  = (win[5 + j] - win[3 + j]) * h2;
        gg[j] = ((win[6 + j] - win[4 + j]) * h2 - (win[4 + j] - win[2 + j]) * h2) * h2;
    }
    if (x0 == 0) {
        g[0]  = (C[1] - C[0]) * h1;
        gg[0] = ((C[2] - C[0]) * h2 - g[0]) * h1;
        gg[1] = ((C[3] - C[1]) * h2 - (C[1] - C[0]) * h1) * h2;
    } else if (x0 == NX - 4) {
        gg[2] = ((C[3] - C[2]) * h1 - (C[2] - C[0]) * h2) * h2;
        g[3]  = (C[3] - C[2]) * h1;
        gg[3] = (g[3] - (C[3] - C[1]) * h2) * h1;
    }
}

__device__ __forceinline__ f4 grad1x(f4 L, f4 C, f4 R, int x0, float inv_h) {
    const float h1 = inv_h, h2 = 0.5f * inv_h;
    f4 g;
    g[0] = (C[1] - L[3]) * h2;
    g[1] = (C[2] - C[0]) * h2;
    g[2] = (C[3] - C[1]) * h2;
    g[3] = (R[0] - C[2]) * h2;
    if (x0 == 0)            g[0] = (C[1] - C[0]) * h1;
    else if (x0 == NX - 4)  g[3] = (C[3] - C[2]) * h1;
    return g;
}

// ---- y/z axes: whole-vector stencil, index i uniform across the f4 ----
__device__ __forceinline__ void grad2v(f4 m2, f4 m1, f4 c, f4 p1, f4 p2,
                                       int i, int n, float inv_h, f4& g, f4& gg) {
    const float h1 = inv_h, h2 = 0.5f * inv_h;
    if (i >= 2 && i <= n - 3) {
        g  = (p1 - m1) * sp(h2);
        gg = ((p2 - c) * sp(h2) - (c - m2) * sp(h2)) * sp(h2);
    } else if (i == 0) {
        g  = (p1 - c) * sp(h1);
        gg = ((p2 - c) * sp(h2) - g) * sp(h1);
    } else if (i == 1) {
        g  = (p1 - m1) * sp(h2);
        gg = ((p2 - c) * sp(h2) - (c - m1) * sp(h1)) * sp(h2);
    } else if (i == n - 2) {
        g  = (p1 - m1) * sp(h2);
        gg = ((p1 - c) * sp(h1) - (c - m2) * sp(h2)) * sp(h2);
    } else { // i == n-1
        g  = (c - m1) * sp(h1);
        gg = (g - (c - m2) * sp(h2)) * sp(h1);
    }
}

__device__ __forceinline__ f4 grad1v(f4 m1, f4 c, f4 p1, int i, int n, float inv_h) {
    if (i == 0)     return (p1 - c) * sp(inv_h);
    if (i == n - 1) return (c - m1) * sp(inv_h);
    return (p1 - m1) * sp(0.5f * inv_h);
}

// ---- paired grad2: points A (x0) and B (x0+4) share the x-window ----
__device__ __forceinline__ void pg2(const float* __restrict__ f, int eA,
        int xm, int xp2,
        int m1y, int m2y, int p1y, int p2y,
        int m1z, int m2z, int p1z, int p2z,
        int x0, int y, int z, f4 CA, f4 CB,
        f4& gxA, f4& gyA, f4& gzA, f4& lapA,
        f4& gxB, f4& gyB, f4& gzB, f4& lapB) {
    const int eB = eA + 4;
    const f4 L   = ldv(f, eA + xm);
    const f4 R   = ldv(f, eA + xp2);
    const f4 y1A = ldv(f, eA + m1y), y2A = ldv(f, eA + m2y);
    const f4 y3A = ldv(f, eA + p1y), y4A = ldv(f, eA + p2y);
    const f4 y1B = ldv(f, eB + m1y), y2B = ldv(f, eB + m2y);
    const f4 y3B = ldv(f, eB + p1y), y4B = ldv(f, eB + p2y);
    const f4 z1A = ldv(f, eA + m1z), z2A = ldv(f, eA + m2z);
    const f4 z3A = ldv(f, eA + p1z), z4A = ldv(f, eA + p2z);
    const f4 z1B = ldv(f, eB + m1z), z2B = ldv(f, eB + m2z);
    const f4 z3B = ldv(f, eB + p1z), z4B = ldv(f, eB + p2z);
    f4 gg;
    grad2x(L, CA, CB, x0, INV_DX, gxA, gg);               lapA = gg;
    grad2x(CA, CB, R, x0 + 4, INV_DX, gxB, gg);           lapB = gg;
    grad2v(y2A, y1A, CA, y3A, y4A, y, NY, INV_DY, gyA, gg); lapA += gg;
    grad2v(y2B, y1B, CB, y3B, y4B, y, NY, INV_DY, gyB, gg); lapB += gg;
    grad2v(z2A, z1A, CA, z3A, z4A, z, NZ, INV_DZ, gzA, gg); lapA += gg;
    grad2v(z2B, z1B, CB, z3B, z4B, z, NZ, INV_DZ, gzB, gg); lapB += gg;
}

// ---- paired grad1 ----
__device__ __forceinline__ void pg1(const float* __restrict__ f, int eA,
        int xm, int xp2, int m1y, int p1y, int m1z, int p1z,
        int x0, int y, int z, f4 CA, f4 CB,
        f4& gxA, f4& gyA, f4& gzA,
        f4& gxB, f4& gyB, f4& gzB) {
    const int eB = eA + 4;
    const f4 L   = ldv(f, eA + xm);
    const f4 R   = ldv(f, eA + xp2);
    const f4 y1A = ldv(f, eA + m1y), y3A = ldv(f, eA + p1y);
    const f4 y1B = ldv(f, eB + m1y), y3B = ldv(f, eB + p1y);
    const f4 z1A = ldv(f, eA + m1z), z3A = ldv(f, eA + p1z);
    const f4 z1B = ldv(f, eB + m1z), z3B = ldv(f, eB + p1z);
    gxA = grad1x(L, CA, CB, x0, INV_DX);
    gxB = grad1x(CA, CB, R, x0 + 4, INV_DX);
    gyA = grad1v(y1A, CA, y3A, y, NY, INV_DY);
    gyB = grad1v(y1B, CB, y3B, y, NY, INV_DY);
    gzA = grad1v(z1A, CA, z3A, z, NZ, INV_DZ);
    gzB = grad1v(z1B, CB, z3B, z, NZ, INV_DZ);
}

// Paired-point fat-wave kernel: each thread owns f4 A (x0) and B (x0+4) —
// two independent dependency chains double per-wave loads-in-flight (the
// r11-confirmed lever), and the shared x-window saves 7 loads/pair.
__global__ __launch_bounds__(256, 2)
void pe_pair(const float* __restrict__ u, const float* __restrict__ v,
             const float* __restrict__ w, const float* __restrict__ T,
             const float* __restrict__ q, const float* __restrict__ p,
             const float* __restrict__ rho,
             const float* __restrict__ F_u, const float* __restrict__ F_v,
             const float* __restrict__ F_w, const float* __restrict__ Q,
             const float* __restrict__ S,
             const float* __restrict__ nu_p, const float* __restrict__ kappa_p,
             float* __restrict__ out) {
    // XCD-aware map: xcd = bid&7 owns a 32-row y-band (8 blocks of 4 rows),
    // swept z-major. One wave = one full x-row.
    const int bid = blockIdx.x;
    const int xcd = bid & 7;
    const int j = bid >> 3;                 // 0..383
    const int z = j >> 3;                   // 0..47
    const int ytile = j & 7;                // 0..7
    const int y = (xcd << 5) | (ytile << 2) | (threadIdx.x >> 6);
    const int x0 = (threadIdx.x & 63) << 3; // 0,8,...,504
    const int e = z * SZ + y * SY + x0;     // point A; point B = e+4

    const int xm  = (x0 > 0) ? -4 : 0;
    const int xp2 = (x0 < NX - 8) ? 8 : 4;
    const int m1y = (y > 0) ? -SY : 0;
    const int m2y = (y > 1) ? -2 * SY : m1y;
    const int p1y = (y < NY - 1) ? SY : 0;
    const int p2y = (y < NY - 2) ? 2 * SY : p1y;
    const int m1z = (z > 0) ? -SZ : 0;
    const int m2z = (z > 1) ? -2 * SZ : m1z;
    const int p1z = (z < NZ - 1) ? SZ : 0;
    const int p2z = (z < NZ - 2) ? 2 * SZ : p1z;

    // streamed-once forcings, non-temporal, issued first
    const f4 fFuA = ntldv(F_u, e), fFuB = ntldv(F_u, e + 4);
    const f4 fFvA = ntldv(F_v, e), fFvB = ntldv(F_v, e + 4);
    const f4 fFwA = ntldv(F_w, e), fFwB = ntldv(F_w, e + 4);
    const f4 fQA  = ntldv(Q, e),   fQB  = ntldv(Q, e + 4);
    const f4 fSA  = ntldv(S, e),   fSB  = ntldv(S, e + 4);

    // centers
    const f4 uA = ldv(u, e), uB = ldv(u, e + 4);
    const f4 vA = ldv(v, e), vB = ldv(v, e + 4);
    const f4 wA = ldv(w, e), wB = ldv(w, e + 4);
    const f4 pA = ldv(p, e), pB = ldv(p, e + 4);
    const f4 rA = ldv(rho, e), rB = ldv(rho, e + 4);

    const float snu = nu_p[0];
    const float skap = kappa_p[0];
    const float lat = -1.57079632679f + (3.14159265359f / 255.0f) * (float)y;
    const float fc = 2.0f * 7.2921e-5f * __sinf(lat);

    f4 gxA, gyA, gzA, lapA, gxB, gyB, gzB, lapB;

    // ---- u ----
    pg2(u, e, xm, xp2, m1y, m2y, p1y, p2y, m1z, m2z, p1z, p2z, x0, y, z,
        uA, uB, gxA, gyA, gzA, lapA, gxB, gyB, gzB, lapB);
    const f4 dudxA = gxA, dudxB = gxB;
    f4 accuA = sp(snu) * lapA - (uA * gxA + vA * gyA + wA * gzA);
    f4 accuB = sp(snu) * lapB - (uB * gxB + vB * gyB + wB * gzB);

    // ---- v ----
    pg2(v, e, xm, xp2, m1y, m2y, p1y, p2y, m1z, m2z, p1z, p2z, x0, y, z,
        vA, vB, gxA, gyA, gzA, lapA, gxB, gyB, gzB, lapB);
    const f4 dvdyA = gyA, dvdyB = gyB;
    f4 accvA = sp(snu) * lapA - (uA * gxA + vA * gyA + wA * gzA);
    f4 accvB = sp(snu) * lapB - (uB * gxB + vB * gyB + wB * gzB);

    // ---- w ----
    pg2(w, e, xm, xp2, m1y, m2y, p1y, p2y, m1z, m2z, p1z, p2z, x0, y, z,
        wA, wB, gxA, gyA, gzA, lapA, gxB, gyB, gzB, lapB);
    const f4 dwdzA = gzA, dwdzB = gzB;
    f4 accwA = sp(snu) * lapA - (uA * gxA + vA * gyA + wA * gzA);
    f4 accwB = sp(snu) * lapB - (uB * gxB + vB * gyB + wB * gzB);

    const f4 divA = dudxA + dvdyA + dwdzA;
    const f4 divB = dudxB + dvdyB + dwdzB;

    // ---- p (grad1) ----
    f4 gpxA, gpyA, dpzA, gpxB, gpyB, dpzB;
    pg1(p, e, xm, xp2, m1y, p1y, m1z, p1z, x0, y, z, pA, pB,
        gpxA, gpyA, dpzA, gpxB, gpyB, dpzB);

    const f4 irsA = sp(1.0f) / (rA + sp(1e-10f));
    const f4 irsB = sp(1.0f) / (rB + sp(1e-10f));
    accuA += fFuA - gpxA * irsA + sp(fc) * vA;
    accuB += fFuB - gpxB * irsB + sp(fc) * vB;
    accvA += fFvA - gpyA * irsA - sp(fc) * uA;
    accvB += fFvB - gpyB * irsB - sp(fc) * uB;
    accwA += fFwA - dpzA * irsA - sp(9.80665f);
    accwB += fFwB - dpzB * irsB - sp(9.80665f);

    *reinterpret_cast<f4*>(out + 0 * NTOT + e)     = accuA;
    *reinterpret_cast<f4*>(out + 0 * NTOT + e + 4) = accuB;
    *reinterpret_cast<f4*>(out + 1 * NTOT + e)     = accvA;
    *reinterpret_cast<f4*>(out + 1 * NTOT + e + 4) = accvB;
    *reinterpret_cast<f4*>(out + 2 * NTOT + e)     = accwA;
    *reinterpret_cast<f4*>(out + 2 * NTOT + e + 4) = accwB;

    // ---- T ----
    const f4 TA = ldv(T, e), TB = ldv(T, e + 4);
    pg2(T, e, xm, xp2, m1y, m2y, p1y, p2y, m1z, m2z, p1z, p2z, x0, y, z,
        TA, TB, gxA, gyA, gzA, lapA, gxB, gyB, gzB, lapB);
    f4 accTA = sp(skap) * lapA - (uA * gxA + vA * gyA + wA * gzA);
    f4 accTB = sp(skap) * lapB - (uB * gxB + vB * gyB + wB * gzB);
    accTA += sp(287.0f / 1004.0f) * TA * wA * dpzA / (pA + sp(1e-10f));
    accTB += sp(287.0f / 1004.0f) * TB * wB * dpzB / (pB + sp(1e-10f));
    accTA += fQA * sp(1.0f / 1004.0f);
    accTB += fQB * sp(1.0f / 1004.0f);

    // ---- q (grad1) ----
    const f4 qA = ldv(q, e), qB = ldv(q, e + 4);
    pg1(q, e, xm, xp2, m1y, p1y, m1z, p1z, x0, y, z, qA, qB,
        gxA, gyA, gzA, gxB, gyB, gzB);
    const f4 accqA = fSA - (uA * gxA + vA * gyA + wA * gzA);
    const f4 accqB = fSB - (uB * gxB + vB * gyB + wB * gzB);

    // ---- rho (grad1) ----
    pg1(rho, e, xm, xp2, m1y, p1y, m1z, p1z, x0, y, z, rA, rB,
        gxA, gyA, gzA, gxB, gyB, gzB);
    const f4 accrA = -rA * divA - uA * gxA - vA * gyA - wA * gzA;
    const f4 accrB = -rB * divB - uB * gxB - vB * gyB - wB * gzB;

    const f4 accpA = sp(287.0f) * (rA * accTA + TA * accrA);
    const f4 accpB = sp(287.0f) * (rB * accTB + TB * accrB);

    *reinterpret_cast<f4*>(out + 3 * NTOT + e)     = accTA;
    *reinterpret_cast<f4*>(out + 3 * NTOT + e + 4) = accTB;
    *reinterpret_cast<f4*>(out + 4 * NTOT + e)     = accqA;
    *reinterpret_cast<f4*>(out + 4 * NTOT + e + 4) = accqB;
    *reinterpret_cast<f4*>(out + 5 * NTOT + e)     = accpA;
    *reinterpret_cast<f4*>(out + 5 * NTOT + e + 4) = accpB;
    *reinterpret_cast<f4*>(out + 6 * NTOT + e)     = accrA;
    *reinterpret_cast<f4*>(out + 6 * NTOT + e + 4) = accrB;
}

extern "C" void kernel_launch(void* const* d_in, const int* in_sizes, int n_in,
                              void* d_out, int out_size, void* d_ws, size_t ws_size,
                              hipStream_t stream) {
    const float* u     = (const float*)d_in[0];
    const float* v     = (const float*)d_in[1];
    const float* w     = (const float*)d_in[2];
    const float* T     = (const float*)d_in[3];
    const float* q     = (const float*)d_in[4];
    const float* p     = (const float*)d_in[5];
    const float* rho   = (const float*)d_in[6];
    const float* F_u   = (const float*)d_in[7];
    const float* F_v   = (const float*)d_in[8];
    const float* F_w   = (const float*)d_in[9];
    const float* Q     = (const float*)d_in[10];
    const float* S     = (const float*)d_in[11];
    const float* nu    = (const float*)d_in[12];
    const float* kappa = (const float*)d_in[13];
    float* out = (float*)d_out;

    // 48 z * 8 y-tiles * 8 XCDs = 3072 blocks (4 rows per block)
    pe_pair<<<3072, 256, 0, stream>>>(u, v, w, T, q, p, rho,
                                      F_u, F_v, F_w, Q, S, nu, kappa, out);
}